// Round 3
// baseline (832.142 us; speedup 1.0000x reference)
//
#include <hip/hip_runtime.h>
#include <hip/hip_bf16.h>

#define S_LEN 2000
#define S_PAD 2048
#define NQKV 6144
#define QUANT_LEN 1920

typedef short short8 __attribute__((ext_vector_type(8)));
typedef float f32x4 __attribute__((ext_vector_type(4)));

__device__ __forceinline__ short f2b(float f) {
  unsigned u = __builtin_bit_cast(unsigned, f);
  u += 0x7fffu + ((u >> 16) & 1u);
  return (short)(u >> 16);
}
__device__ __forceinline__ float b2f(short s) {
  unsigned u = ((unsigned)(unsigned short)s) << 16;
  return __builtin_bit_cast(float, u);
}

// ---------------- conversion kernels ----------------

// hidden -> bf16 hi + bf16 lo (split precision), rows >= S_LEN zeroed
__global__ __launch_bounds__(256) void cvt_hidden2(const float* __restrict__ src, short* __restrict__ hi,
                                                   short* __restrict__ lo) {
  long base = ((long)blockIdx.x * 256 + threadIdx.x) * 8;
  int row = (int)(base >> 12);  // /4096
  short8 h, l;
  if (row < S_LEN) {
#pragma unroll
    for (int j = 0; j < 8; ++j) {
      float x = src[base + j];
      short hb = f2b(x);
      h[j] = hb;
      l[j] = f2b(x - b2f(hb));
    }
  } else {
#pragma unroll
    for (int j = 0; j < 8; ++j) { h[j] = 0; l[j] = 0; }
  }
  *(short8*)(hi + base) = h;
  *(short8*)(lo + base) = l;
}

// dst[n*K + k] = bf16(src[k*N + n]); 32x32 tiles
__global__ __launch_bounds__(256) void transpose_cvt(const float* __restrict__ src, short* __restrict__ dst,
                                                     int K, int N) {
  __shared__ float t[32][33];
  int n0 = blockIdx.x * 32, k0 = blockIdx.y * 32;
  int tx = threadIdx.x & 31, ty = threadIdx.x >> 5;
#pragma unroll
  for (int i = 0; i < 4; ++i)
    t[ty + i * 8][tx] = src[(long)(k0 + ty + i * 8) * N + n0 + tx];
  __syncthreads();
#pragma unroll
  for (int i = 0; i < 4; ++i)
    dst[(long)(n0 + ty + i * 8) * K + k0 + tx] = f2b(t[tx][ty + i * 8]);
}

// split-precision transpose: hi + lo
__global__ __launch_bounds__(256) void transpose_cvt2(const float* __restrict__ src, short* __restrict__ dhi,
                                                      short* __restrict__ dlo, int K, int N) {
  __shared__ float t[32][33];
  int n0 = blockIdx.x * 32, k0 = blockIdx.y * 32;
  int tx = threadIdx.x & 31, ty = threadIdx.x >> 5;
#pragma unroll
  for (int i = 0; i < 4; ++i)
    t[ty + i * 8][tx] = src[(long)(k0 + ty + i * 8) * N + n0 + tx];
  __syncthreads();
#pragma unroll
  for (int i = 0; i < 4; ++i) {
    float x = t[tx][ty + i * 8];
    short hb = f2b(x);
    long idx = (long)(n0 + ty + i * 8) * K + k0 + tx;
    dhi[idx] = hb;
    dlo[idx] = f2b(x - b2f(hb));
  }
}

// ---------------- bf16 MFMA GEMM: C[M][*] = A[M][K] * BT[N][K]^T ----------------

__global__ __launch_bounds__(256) void gemm_bt(const short* __restrict__ A, const short* __restrict__ BT,
                                               float* __restrict__ C, int M_store, int ldc, int K) {
  __shared__ short As[128][72];
  __shared__ short Bs[128][72];
  int m0 = blockIdx.y * 128, n0 = blockIdx.x * 128;
  int t = threadIdx.x, lane = t & 63, w = t >> 6;
  int wm = w >> 1, wn = w & 1;
  int lr = lane & 15, lg = lane >> 4;
  int r_s = t >> 1, cs = (t & 1) * 32;
  f32x4 acc[4][4];
#pragma unroll
  for (int mi = 0; mi < 4; ++mi)
#pragma unroll
    for (int ni = 0; ni < 4; ++ni) acc[mi][ni] = f32x4{0.f, 0.f, 0.f, 0.f};
  const int nk = K >> 6;
  const short* Ap = A + (long)(m0 + r_s) * K + cs;
  const short* Bp = BT + (long)(n0 + r_s) * K + cs;
  for (int kt = 0; kt < nk; ++kt) {
    __syncthreads();
#pragma unroll
    for (int j = 0; j < 4; ++j) {
      *(short8*)&As[r_s][cs + j * 8] = *(const short8*)(Ap + kt * 64 + j * 8);
      *(short8*)&Bs[r_s][cs + j * 8] = *(const short8*)(Bp + kt * 64 + j * 8);
    }
    __syncthreads();
#pragma unroll
    for (int kk = 0; kk < 2; ++kk) {
      short8 a[4], b[4];
#pragma unroll
      for (int i = 0; i < 4; ++i) a[i] = *(const short8*)&As[wm * 64 + i * 16 + lr][kk * 32 + lg * 8];
#pragma unroll
      for (int i = 0; i < 4; ++i) b[i] = *(const short8*)&Bs[wn * 64 + i * 16 + lr][kk * 32 + lg * 8];
#pragma unroll
      for (int mi = 0; mi < 4; ++mi)
#pragma unroll
        for (int ni = 0; ni < 4; ++ni)
          acc[mi][ni] = __builtin_amdgcn_mfma_f32_16x16x32_bf16(a[mi], b[ni], acc[mi][ni], 0, 0, 0);
    }
  }
#pragma unroll
  for (int mi = 0; mi < 4; ++mi)
#pragma unroll
    for (int i = 0; i < 4; ++i) {
      int row = m0 + wm * 64 + mi * 16 + lg * 4 + i;
      if (row < M_store) {
#pragma unroll
        for (int ni = 0; ni < 4; ++ni)
          C[(long)row * ldc + n0 + wn * 64 + ni * 16 + lr] = acc[mi][ni][i];
      }
    }
}

// split-bf16 GEMM: effective-fp32 via (Ahi+Alo)*(Bhi+Blo) ~ hi*hi + hi*lo + lo*hi
__global__ __launch_bounds__(256) void gemm_bt_split(const short* __restrict__ Ahi, const short* __restrict__ Alo,
                                                     const short* __restrict__ Bhi, const short* __restrict__ Blo,
                                                     float* __restrict__ C, int M_store, int ldc, int K) {
  __shared__ short Ash[128][72], Asl[128][72];
  __shared__ short Bsh[128][72], Bsl[128][72];
  int m0 = blockIdx.y * 128, n0 = blockIdx.x * 128;
  int t = threadIdx.x, lane = t & 63, w = t >> 6;
  int wm = w >> 1, wn = w & 1;
  int lr = lane & 15, lg = lane >> 4;
  int r_s = t >> 1, cs = (t & 1) * 32;
  f32x4 acc[4][4];
#pragma unroll
  for (int mi = 0; mi < 4; ++mi)
#pragma unroll
    for (int ni = 0; ni < 4; ++ni) acc[mi][ni] = f32x4{0.f, 0.f, 0.f, 0.f};
  const int nk = K >> 6;
  long aoff = (long)(m0 + r_s) * K + cs;
  long boff = (long)(n0 + r_s) * K + cs;
  for (int kt = 0; kt < nk; ++kt) {
    __syncthreads();
#pragma unroll
    for (int j = 0; j < 4; ++j) {
      *(short8*)&Ash[r_s][cs + j * 8] = *(const short8*)(Ahi + aoff + kt * 64 + j * 8);
      *(short8*)&Asl[r_s][cs + j * 8] = *(const short8*)(Alo + aoff + kt * 64 + j * 8);
      *(short8*)&Bsh[r_s][cs + j * 8] = *(const short8*)(Bhi + boff + kt * 64 + j * 8);
      *(short8*)&Bsl[r_s][cs + j * 8] = *(const short8*)(Blo + boff + kt * 64 + j * 8);
    }
    __syncthreads();
#pragma unroll
    for (int kk = 0; kk < 2; ++kk) {
      short8 ah[4], al[4], bh[4], bl[4];
#pragma unroll
      for (int i = 0; i < 4; ++i) {
        ah[i] = *(const short8*)&Ash[wm * 64 + i * 16 + lr][kk * 32 + lg * 8];
        al[i] = *(const short8*)&Asl[wm * 64 + i * 16 + lr][kk * 32 + lg * 8];
        bh[i] = *(const short8*)&Bsh[wn * 64 + i * 16 + lr][kk * 32 + lg * 8];
        bl[i] = *(const short8*)&Bsl[wn * 64 + i * 16 + lr][kk * 32 + lg * 8];
      }
#pragma unroll
      for (int mi = 0; mi < 4; ++mi)
#pragma unroll
        for (int ni = 0; ni < 4; ++ni) {
          acc[mi][ni] = __builtin_amdgcn_mfma_f32_16x16x32_bf16(ah[mi], bh[ni], acc[mi][ni], 0, 0, 0);
          acc[mi][ni] = __builtin_amdgcn_mfma_f32_16x16x32_bf16(ah[mi], bl[ni], acc[mi][ni], 0, 0, 0);
          acc[mi][ni] = __builtin_amdgcn_mfma_f32_16x16x32_bf16(al[mi], bh[ni], acc[mi][ni], 0, 0, 0);
        }
    }
  }
#pragma unroll
  for (int mi = 0; mi < 4; ++mi)
#pragma unroll
    for (int i = 0; i < 4; ++i) {
      int row = m0 + wm * 64 + mi * 16 + lg * 4 + i;
      if (row < M_store) {
#pragma unroll
        for (int ni = 0; ni < 4; ++ni)
          C[(long)row * ldc + n0 + wn * 64 + ni * 16 + lr] = acc[mi][ni][i];
      }
    }
}

// ---------------- RoPE ----------------
// qkv row layout [s][6144]: q cols 0..4095, k cols 4096..5119, v cols 5120..6143
__global__ __launch_bounds__(256) void rope_kernel(const float* __restrict__ qkv, short* __restrict__ qb,
                                                   float* __restrict__ kr) {
  __shared__ float invt[64];
  if (threadIdx.x < 64) invt[threadIdx.x] = (float)pow(10000.0, -(double)threadIdx.x / 64.0);
  __syncthreads();
  int s = blockIdx.x;  // 0..2047
  bool valid = s < S_LEN;
  for (int p = threadIdx.x; p < 2560; p += 256) {
    int hh = p >> 6, j = p & 63;
    float ang = (float)s * invt[j];
    float c = cosf(ang), sn = sinf(ang);
    if (hh < 32) {
      long base = (long)s * NQKV + (long)hh * 128;
      float x1 = valid ? qkv[base + j] : 0.f;
      float x2 = valid ? qkv[base + j + 64] : 0.f;
      long ob = ((long)hh * S_PAD + s) * 128;
      qb[ob + j] = f2b(x1 * c - x2 * sn);
      qb[ob + j + 64] = f2b(x2 * c + x1 * sn);
    } else {
      int h = hh - 32;
      long base = (long)s * NQKV + 4096 + (long)h * 128;
      float x1 = valid ? qkv[base + j] : 0.f;
      float x2 = valid ? qkv[base + j + 64] : 0.f;
      long ob = ((long)h * S_PAD + s) * 128;
      kr[ob + j] = valid ? (x1 * c - x2 * sn) : 0.f;
      kr[ob + j + 64] = valid ? (x2 * c + x1 * sn) : 0.f;
    }
  }
}

// ---------------- K stats ----------------

__global__ __launch_bounds__(128) void kstat_partial(const float* __restrict__ kr, float* __restrict__ psum,
                                                     float* __restrict__ pmax) {
  int h = blockIdx.x, chunk = blockIdx.y, d = threadIdx.x;
  float sm = 0.f, mx = 0.f;
  int s0 = chunk * 100, s1 = s0 + 100;
  for (int s = s0; s < s1; ++s) {
    float v = kr[((long)h * S_PAD + s) * 128 + d];
    sm += v;
    mx = fmaxf(mx, fabsf(v));
  }
  psum[(h * 20 + chunk) * 128 + d] = sm;
  pmax[(h * 20 + chunk) * 128 + d] = mx;
}

__global__ __launch_bounds__(128) void kstat_final(const float* __restrict__ psum, const float* __restrict__ pmax,
                                                   float* __restrict__ bias, float* __restrict__ scale) {
  int h = blockIdx.x, d = threadIdx.x;
  float sm = 0.f, mx = 0.f;
  for (int c = 0; c < 20; ++c) {
    sm += psum[(h * 20 + c) * 128 + d];
    mx = fmaxf(mx, pmax[(h * 20 + c) * 128 + d]);
  }
  bias[h * 128 + d] = sm / 2000.0f;
  scale[h * 128 + d] = powf(mx, 0.6f);
}

// ---------------- quant-dequant K -> bf16 [h][s][d] ----------------

__global__ __launch_bounds__(256) void quant_k(const float* __restrict__ kr, const float* __restrict__ bias,
                                               const float* __restrict__ scale, short* __restrict__ kb) {
  int gid = blockIdx.x * 4 + (threadIdx.x >> 6);
  int lane = threadIdx.x & 63;
  int h = gid >> 11, s = gid & 2047;
  long base = ((long)h * S_PAD + s) * 128;
  if (s >= S_LEN) {
    kb[base + lane] = 0;
    kb[base + lane + 64] = 0;
    return;
  }
  float x0 = kr[base + lane], x1 = kr[base + lane + 64];
  float o0, o1;
  if (s >= QUANT_LEN) {
    o0 = x0;
    o1 = x1;
  } else {
    float b0 = bias[h * 128 + lane], b1 = bias[h * 128 + lane + 64];
    float c0 = scale[h * 128 + lane], c1 = scale[h * 128 + lane + 64];
    float kh0 = (x0 - b0) / c0, kh1 = (x1 - b1) / c1;
    float mn0 = kh0, mx0 = kh0, mn1 = kh1, mx1 = kh1;
#pragma unroll
    for (int off = 1; off < 64; off <<= 1) {
      mn0 = fminf(mn0, __shfl_xor(mn0, off));
      mx0 = fmaxf(mx0, __shfl_xor(mx0, off));
      mn1 = fminf(mn1, __shfl_xor(mn1, off));
      mx1 = fmaxf(mx1, __shfl_xor(mx1, off));
    }
    float s0 = fmaxf((mx0 - mn0) / 15.f, 1e-8f), s1 = fmaxf((mx1 - mn1) / 15.f, 1e-8f);
    float q0 = fminf(fmaxf(rintf((kh0 - mn0) / s0), 0.f), 15.f);
    float q1 = fminf(fmaxf(rintf((kh1 - mn1) / s1), 0.f), 15.f);
    o0 = (q0 * s0 + mn0) * c0 + b0;
    o1 = (q1 * s1 + mn1) * c1 + b1;
  }
  kb[base + lane] = f2b(o0);
  kb[base + lane + 64] = f2b(o1);
}

// ---------------- quant-dequant V -> bf16 transposed [h][d][s] ----------------

__global__ __launch_bounds__(256) void quant_v(const float* __restrict__ qkv, short* __restrict__ vt) {
  int gid = blockIdx.x * 4 + (threadIdx.x >> 6);
  int lane = threadIdx.x & 63;
  int h = gid >> 11, s = gid & 2047;
  float o0 = 0.f, o1 = 0.f;
  if (s < S_LEN) {
    long base = (long)s * NQKV + 5120 + (long)h * 128;
    float x0 = qkv[base + lane], x1 = qkv[base + lane + 64];
    if (s >= QUANT_LEN) {
      o0 = x0;
      o1 = x1;
    } else {
      float mn0 = x0, mx0 = x0, mn1 = x1, mx1 = x1;
#pragma unroll
      for (int off = 1; off < 64; off <<= 1) {
        mn0 = fminf(mn0, __shfl_xor(mn0, off));
        mx0 = fmaxf(mx0, __shfl_xor(mx0, off));
        mn1 = fminf(mn1, __shfl_xor(mn1, off));
        mx1 = fmaxf(mx1, __shfl_xor(mx1, off));
      }
      float s0 = fmaxf((mx0 - mn0) / 15.f, 1e-8f), s1 = fmaxf((mx1 - mn1) / 15.f, 1e-8f);
      float q0 = fminf(fmaxf(rintf((x0 - mn0) / s0), 0.f), 15.f);
      float q1 = fminf(fmaxf(rintf((x1 - mn1) / s1), 0.f), 15.f);
      o0 = q0 * s0 + mn0;
      o1 = q1 * s1 + mn1;
    }
  }
  long ob = (long)h * 128 * S_PAD;
  vt[ob + (long)lane * S_PAD + s] = f2b(o0);
  vt[ob + (long)(lane + 64) * S_PAD + s] = f2b(o1);
}

// ---------------- flash attention ----------------
// qb [32][2048][128], kb [8][2048][128], vt [8][128][2048], ao [2048][4096]

__global__ __launch_bounds__(256) void flash_attn(const short* __restrict__ qb, const short* __restrict__ kb,
                                                  const short* __restrict__ vt, short* __restrict__ ao) {
  __shared__ short Ks[64][136];
  __shared__ short Vs[128][72];
  __shared__ short Ps[4][16][72];
  int qt = blockIdx.x, h = blockIdx.y;
  int kvh = h >> 2;
  int t = threadIdx.x, lane = t & 63, w = t >> 6;
  int lr = lane & 15, lg = lane >> 4;
  int qrow = qt * 64 + w * 16;
  short8 qf[4];
#pragma unroll
  for (int kk = 0; kk < 4; ++kk)
    qf[kk] = *(const short8*)(qb + ((long)h * S_PAD + qrow + lr) * 128 + kk * 32 + lg * 8);
  f32x4 o[8];
#pragma unroll
  for (int nb = 0; nb < 8; ++nb) o[nb] = f32x4{0.f, 0.f, 0.f, 0.f};
  float m_i[4], l_i[4];
#pragma unroll
  for (int i = 0; i < 4; ++i) {
    m_i[i] = -1e30f;
    l_i[i] = 0.f;
  }
  const float sm_scale = 0.08838834764831845f;  // 1/sqrt(128)
  int nkt = qt + 1;
  for (int kt = 0; kt < nkt; ++kt) {
    __syncthreads();
    {
      int r = t >> 2, cc = (t & 3) * 32;
      const short* src = kb + ((long)kvh * S_PAD + kt * 64 + r) * 128 + cc;
#pragma unroll
      for (int j = 0; j < 4; ++j) *(short8*)&Ks[r][cc + j * 8] = *(const short8*)(src + j * 8);
    }
    {
      int d = t >> 1, cc = (t & 1) * 32;
      const short* src = vt + ((long)kvh * 128 + d) * S_PAD + kt * 64 + cc;
#pragma unroll
      for (int j = 0; j < 4; ++j) *(short8*)&Vs[d][cc + j * 8] = *(const short8*)(src + j * 8);
    }
    __syncthreads();
    f32x4 sc[4];
#pragma unroll
    for (int nb = 0; nb < 4; ++nb) sc[nb] = f32x4{0.f, 0.f, 0.f, 0.f};
#pragma unroll
    for (int kk = 0; kk < 4; ++kk) {
#pragma unroll
      for (int nb = 0; nb < 4; ++nb) {
        short8 bk = *(const short8*)&Ks[nb * 16 + lr][kk * 32 + lg * 8];
        sc[nb] = __builtin_amdgcn_mfma_f32_16x16x32_bf16(qf[kk], bk, sc[nb], 0, 0, 0);
      }
    }
    float mrow[4];
#pragma unroll
    for (int i = 0; i < 4; ++i) mrow[i] = -1e30f;
#pragma unroll
    for (int nb = 0; nb < 4; ++nb) {
      int key = kt * 64 + nb * 16 + lr;
#pragma unroll
      for (int i = 0; i < 4; ++i) {
        int qr = qrow + lg * 4 + i;
        float v = sc[nb][i] * sm_scale + (key > qr ? -1e9f : 0.f);
        sc[nb][i] = v;
        mrow[i] = fmaxf(mrow[i], v);
      }
    }
#pragma unroll
    for (int off = 1; off < 16; off <<= 1)
#pragma unroll
      for (int i = 0; i < 4; ++i) mrow[i] = fmaxf(mrow[i], __shfl_xor(mrow[i], off));
    float mnew[4], fac[4], rsum[4];
#pragma unroll
    for (int i = 0; i < 4; ++i) {
      mnew[i] = fmaxf(m_i[i], mrow[i]);
      fac[i] = __expf(m_i[i] - mnew[i]);
      m_i[i] = mnew[i];
      rsum[i] = 0.f;
    }
#pragma unroll
    for (int nb = 0; nb < 4; ++nb)
#pragma unroll
      for (int i = 0; i < 4; ++i) {
        float p = __expf(sc[nb][i] - mnew[i]);
        sc[nb][i] = p;
        rsum[i] += p;
      }
#pragma unroll
    for (int off = 1; off < 16; off <<= 1)
#pragma unroll
      for (int i = 0; i < 4; ++i) rsum[i] += __shfl_xor(rsum[i], off);
#pragma unroll
    for (int i = 0; i < 4; ++i) l_i[i] = l_i[i] * fac[i] + rsum[i];
#pragma unroll
    for (int nb = 0; nb < 8; ++nb)
#pragma unroll
      for (int i = 0; i < 4; ++i) o[nb][i] *= fac[i];
#pragma unroll
    for (int nb = 0; nb < 4; ++nb)
#pragma unroll
      for (int i = 0; i < 4; ++i) Ps[w][lg * 4 + i][nb * 16 + lr] = f2b(sc[nb][i]);
#pragma unroll
    for (int kkk = 0; kkk < 2; ++kkk) {
      short8 pa = *(const short8*)&Ps[w][lr][kkk * 32 + lg * 8];
#pragma unroll
      for (int nb = 0; nb < 8; ++nb) {
        short8 bv = *(const short8*)&Vs[nb * 16 + lr][kkk * 32 + lg * 8];
        o[nb] = __builtin_amdgcn_mfma_f32_16x16x32_bf16(pa, bv, o[nb], 0, 0, 0);
      }
    }
  }
  float linv[4];
#pragma unroll
  for (int i = 0; i < 4; ++i) linv[i] = 1.0f / l_i[i];
#pragma unroll
  for (int nb = 0; nb < 8; ++nb)
#pragma unroll
    for (int i = 0; i < 4; ++i) {
      int s = qrow + lg * 4 + i;
      ao[(long)s * 4096 + h * 128 + nb * 16 + lr] = f2b(o[nb][i] * linv[i]);
    }
}

// ---------------- launcher ----------------

extern "C" void kernel_launch(void* const* d_in, const int* in_sizes, int n_in,
                              void* d_out, int out_size, void* d_ws, size_t ws_size,
                              hipStream_t stream) {
  const float* hidden = (const float*)d_in[0];
  const float* wq = (const float*)d_in[1];
  const float* wk = (const float*)d_in[2];
  const float* wv = (const float*)d_in[3];
  const float* wo = (const float*)d_in[4];
  float* out = (float*)d_out;
  char* ws = (char*)d_ws;
  size_t off = 0;
  auto alloc = [&](size_t bytes) -> void* {
    void* p = ws + off;
    off += (bytes + 255) & ~(size_t)255;
    return p;
  };
  short* wqT = (short*)alloc(4096L * 4096 * 2);       // wq^T bf16
  short* wkvT_hi = (short*)alloc(2048L * 4096 * 2);   // [wk;wv]^T hi
  short* wkvT_lo = (short*)alloc(2048L * 4096 * 2);   // [wk;wv]^T lo
  float* qkvf = (float*)alloc(2048L * 6144 * 4);
  short* hb_hi = (short*)alloc(2048L * 4096 * 2);
  short* hb_lo = (short*)alloc(2048L * 4096 * 2);
  short* qb2 = (short*)alloc(32L * 2048 * 128 * 2);
  float* kr = (float*)alloc(8L * 2048 * 128 * 4);
  short* kbq = (short*)alloc(8L * 2048 * 128 * 2);
  short* vt = (short*)alloc(8L * 128 * 2048 * 2);
  float* psum = (float*)alloc(8L * 20 * 128 * 4);
  float* pmax = (float*)alloc(8L * 20 * 128 * 4);
  float* kbias = (float*)alloc(1024 * 4);
  float* kscale = (float*)alloc(1024 * 4);
  short* woT = (short*)qkvf;  // alias: qkvf dead after quant_v (33.5MB <= 50.3MB)
  short* ab = hb_hi;          // alias: hb_hi dead after QKV GEMMs

  cvt_hidden2<<<4096, 256, 0, stream>>>(hidden, hb_hi, hb_lo);
  transpose_cvt<<<dim3(128, 128), 256, 0, stream>>>(wq, wqT, 4096, 4096);
  transpose_cvt2<<<dim3(32, 128), 256, 0, stream>>>(wk, wkvT_hi, wkvT_lo, 4096, 1024);
  transpose_cvt2<<<dim3(32, 128), 256, 0, stream>>>(wv, wkvT_hi + 1024L * 4096, wkvT_lo + 1024L * 4096, 4096, 1024);
  // Q projection: plain bf16 (scores are insensitive); writes qkvf cols 0..4095
  gemm_bt<<<dim3(32, 16), 256, 0, stream>>>(hb_hi, wqT, qkvf, 2000, 6144, 4096);
  // K,V projection: split-bf16 (quant decisions need fp32-level); writes cols 4096..6143
  gemm_bt_split<<<dim3(16, 16), 256, 0, stream>>>(hb_hi, hb_lo, wkvT_hi, wkvT_lo, qkvf + 4096, 2000, 6144, 4096);
  rope_kernel<<<2048, 256, 0, stream>>>(qkvf, qb2, kr);
  kstat_partial<<<dim3(8, 20), 128, 0, stream>>>(kr, psum, pmax);
  kstat_final<<<8, 128, 0, stream>>>(psum, pmax, kbias, kscale);
  quant_k<<<4096, 256, 0, stream>>>(kr, kbias, kscale, kbq);
  quant_v<<<4096, 256, 0, stream>>>(qkvf, vt);
  transpose_cvt<<<dim3(128, 128), 256, 0, stream>>>(wo, woT, 4096, 4096);
  flash_attn<<<dim3(32, 32), 256, 0, stream>>>(qb2, kbq, vt, ab);
  gemm_bt<<<dim3(32, 16), 256, 0, stream>>>(ab, woT, out, 2000, 4096, 4096);
}

// Round 4
// 680.480 us; speedup vs baseline: 1.2229x; 1.2229x over previous
//
#include <hip/hip_runtime.h>
#include <hip/hip_bf16.h>

#define S_LEN 2000
#define S_PAD 2048
#define NQKV 6144
#define QUANT_LEN 1920

typedef short short8 __attribute__((ext_vector_type(8)));
typedef float f32x4 __attribute__((ext_vector_type(4)));

__device__ __forceinline__ short f2b(float f) {
  unsigned u = __builtin_bit_cast(unsigned, f);
  u += 0x7fffu + ((u >> 16) & 1u);
  return (short)(u >> 16);
}
__device__ __forceinline__ float b2f(short s) {
  unsigned u = ((unsigned)(unsigned short)s) << 16;
  return __builtin_bit_cast(float, u);
}

// async global->LDS, 16B per lane; lds base must be wave-uniform (HW writes base + lane*16)
__device__ __forceinline__ void gl_lds16(const void* g, void* lds) {
  __builtin_amdgcn_global_load_lds((__attribute__((address_space(1))) void*)(void*)g,
                                   (__attribute__((address_space(3))) void*)lds, 16, 0, 0);
}

// ---------------- conversion kernels ----------------

__global__ __launch_bounds__(256) void cvt_hidden2(const float* __restrict__ src, short* __restrict__ hi,
                                                   short* __restrict__ lo) {
  long base = ((long)blockIdx.x * 256 + threadIdx.x) * 8;
  int row = (int)(base >> 12);
  short8 h, l;
  if (row < S_LEN) {
#pragma unroll
    for (int j = 0; j < 8; ++j) {
      float x = src[base + j];
      short hb = f2b(x);
      h[j] = hb;
      l[j] = f2b(x - b2f(hb));
    }
  } else {
#pragma unroll
    for (int j = 0; j < 8; ++j) { h[j] = 0; l[j] = 0; }
  }
  *(short8*)(hi + base) = h;
  *(short8*)(lo + base) = l;
}

__global__ __launch_bounds__(256) void transpose_cvt(const float* __restrict__ src, short* __restrict__ dst,
                                                     int K, int N) {
  __shared__ float t[32][33];
  int n0 = blockIdx.x * 32, k0 = blockIdx.y * 32;
  int tx = threadIdx.x & 31, ty = threadIdx.x >> 5;
#pragma unroll
  for (int i = 0; i < 4; ++i)
    t[ty + i * 8][tx] = src[(long)(k0 + ty + i * 8) * N + n0 + tx];
  __syncthreads();
#pragma unroll
  for (int i = 0; i < 4; ++i)
    dst[(long)(n0 + ty + i * 8) * K + k0 + tx] = f2b(t[tx][ty + i * 8]);
}

__global__ __launch_bounds__(256) void transpose_cvt2(const float* __restrict__ src, short* __restrict__ dhi,
                                                      short* __restrict__ dlo, int K, int N) {
  __shared__ float t[32][33];
  int n0 = blockIdx.x * 32, k0 = blockIdx.y * 32;
  int tx = threadIdx.x & 31, ty = threadIdx.x >> 5;
#pragma unroll
  for (int i = 0; i < 4; ++i)
    t[ty + i * 8][tx] = src[(long)(k0 + ty + i * 8) * N + n0 + tx];
  __syncthreads();
#pragma unroll
  for (int i = 0; i < 4; ++i) {
    float x = t[tx][ty + i * 8];
    short hb = f2b(x);
    long idx = (long)(n0 + ty + i * 8) * K + k0 + tx;
    dhi[idx] = hb;
    dlo[idx] = f2b(x - b2f(hb));
  }
}

// ---------------- bf16 MFMA GEMM (m97 structure): C[M][*] = A[M][K] * BT[N][K]^T ----------------
// linear LDS [128][64], global_load_lds dwordx4 staging, 2-barrier K-loop

__global__ __launch_bounds__(256, 2) void gemm_bt(const short* __restrict__ A, const short* __restrict__ BT,
                                                  float* __restrict__ C, int M_store, int ldc, int K) {
  __shared__ short As[128 * 64];
  __shared__ short Bs[128 * 64];
  int m0 = blockIdx.y * 128, n0 = blockIdx.x * 128;
  int t = threadIdx.x, lane = t & 63, w = t >> 6;
  int wm = w >> 1, wn = w & 1;
  int lr = lane & 15, lg = lane >> 4;
  int srow = lane >> 3, scol = (lane & 7) * 8;  // within-chunk: 8 rows x 64 cols
  f32x4 acc[4][4];
#pragma unroll
  for (int mi = 0; mi < 4; ++mi)
#pragma unroll
    for (int ni = 0; ni < 4; ++ni) acc[mi][ni] = f32x4{0.f, 0.f, 0.f, 0.f};
  const int nk = K >> 6;
  const short* Ab = A + (long)(m0 + w * 32 + srow) * K + scol;
  const short* Bb = BT + (long)(n0 + w * 32 + srow) * K + scol;
  for (int kt = 0; kt < nk; ++kt) {
    __syncthreads();
#pragma unroll
    for (int j = 0; j < 4; ++j) {
      int c = w * 4 + j;  // chunk: rows c*8..c*8+7
      gl_lds16(Ab + (long)j * 8 * K + kt * 64, &As[c * 512]);
      gl_lds16(Bb + (long)j * 8 * K + kt * 64, &Bs[c * 512]);
    }
    __syncthreads();
#pragma unroll
    for (int kk = 0; kk < 2; ++kk) {
      short8 a[4], b[4];
#pragma unroll
      for (int i = 0; i < 4; ++i) a[i] = *(const short8*)&As[(wm * 64 + i * 16 + lr) * 64 + kk * 32 + lg * 8];
#pragma unroll
      for (int i = 0; i < 4; ++i) b[i] = *(const short8*)&Bs[(wn * 64 + i * 16 + lr) * 64 + kk * 32 + lg * 8];
#pragma unroll
      for (int mi = 0; mi < 4; ++mi)
#pragma unroll
        for (int ni = 0; ni < 4; ++ni)
          acc[mi][ni] = __builtin_amdgcn_mfma_f32_16x16x32_bf16(a[mi], b[ni], acc[mi][ni], 0, 0, 0);
    }
  }
#pragma unroll
  for (int mi = 0; mi < 4; ++mi)
#pragma unroll
    for (int i = 0; i < 4; ++i) {
      int row = m0 + wm * 64 + mi * 16 + lg * 4 + i;
      if (row < M_store) {
#pragma unroll
        for (int ni = 0; ni < 4; ++ni)
          C[(long)row * ldc + n0 + wn * 64 + ni * 16 + lr] = acc[mi][ni][i];
      }
    }
}

// split-bf16 GEMM (effective fp32): hi*hi + hi*lo + lo*hi, m97-style staging
__global__ __launch_bounds__(256, 1) void gemm_bt_split(const short* __restrict__ Ahi, const short* __restrict__ Alo,
                                                        const short* __restrict__ Bhi, const short* __restrict__ Blo,
                                                        float* __restrict__ C, int M_store, int ldc, int K) {
  __shared__ short Ash[128 * 64], Asl[128 * 64];
  __shared__ short Bsh[128 * 64], Bsl[128 * 64];
  int m0 = blockIdx.y * 128, n0 = blockIdx.x * 128;
  int t = threadIdx.x, lane = t & 63, w = t >> 6;
  int wm = w >> 1, wn = w & 1;
  int lr = lane & 15, lg = lane >> 4;
  int srow = lane >> 3, scol = (lane & 7) * 8;
  f32x4 acc[4][4];
#pragma unroll
  for (int mi = 0; mi < 4; ++mi)
#pragma unroll
    for (int ni = 0; ni < 4; ++ni) acc[mi][ni] = f32x4{0.f, 0.f, 0.f, 0.f};
  const int nk = K >> 6;
  long abase = (long)(m0 + w * 32 + srow) * K + scol;
  long bbase = (long)(n0 + w * 32 + srow) * K + scol;
  for (int kt = 0; kt < nk; ++kt) {
    __syncthreads();
#pragma unroll
    for (int j = 0; j < 4; ++j) {
      int c = w * 4 + j;
      long ao = abase + (long)j * 8 * K + kt * 64;
      long bo = bbase + (long)j * 8 * K + kt * 64;
      gl_lds16(Ahi + ao, &Ash[c * 512]);
      gl_lds16(Alo + ao, &Asl[c * 512]);
      gl_lds16(Bhi + bo, &Bsh[c * 512]);
      gl_lds16(Blo + bo, &Bsl[c * 512]);
    }
    __syncthreads();
#pragma unroll
    for (int kk = 0; kk < 2; ++kk) {
      short8 ah[4], al[4], bh[4], bl[4];
#pragma unroll
      for (int i = 0; i < 4; ++i) {
        int ro = (wm * 64 + i * 16 + lr) * 64 + kk * 32 + lg * 8;
        int co = (wn * 64 + i * 16 + lr) * 64 + kk * 32 + lg * 8;
        ah[i] = *(const short8*)&Ash[ro];
        al[i] = *(const short8*)&Asl[ro];
        bh[i] = *(const short8*)&Bsh[co];
        bl[i] = *(const short8*)&Bsl[co];
      }
#pragma unroll
      for (int mi = 0; mi < 4; ++mi)
#pragma unroll
        for (int ni = 0; ni < 4; ++ni) {
          acc[mi][ni] = __builtin_amdgcn_mfma_f32_16x16x32_bf16(ah[mi], bh[ni], acc[mi][ni], 0, 0, 0);
          acc[mi][ni] = __builtin_amdgcn_mfma_f32_16x16x32_bf16(ah[mi], bl[ni], acc[mi][ni], 0, 0, 0);
          acc[mi][ni] = __builtin_amdgcn_mfma_f32_16x16x32_bf16(al[mi], bh[ni], acc[mi][ni], 0, 0, 0);
        }
    }
  }
#pragma unroll
  for (int mi = 0; mi < 4; ++mi)
#pragma unroll
    for (int i = 0; i < 4; ++i) {
      int row = m0 + wm * 64 + mi * 16 + lg * 4 + i;
      if (row < M_store) {
#pragma unroll
        for (int ni = 0; ni < 4; ++ni)
          C[(long)row * ldc + n0 + wn * 64 + ni * 16 + lr] = acc[mi][ni][i];
      }
    }
}

// ---------------- RoPE ----------------
__global__ __launch_bounds__(256) void rope_kernel(const float* __restrict__ qkv, short* __restrict__ qb,
                                                   float* __restrict__ kr) {
  __shared__ float invt[64];
  if (threadIdx.x < 64) invt[threadIdx.x] = (float)pow(10000.0, -(double)threadIdx.x / 64.0);
  __syncthreads();
  int s = blockIdx.x;
  bool valid = s < S_LEN;
  for (int p = threadIdx.x; p < 2560; p += 256) {
    int hh = p >> 6, j = p & 63;
    float ang = (float)s * invt[j];
    float c = cosf(ang), sn = sinf(ang);
    if (hh < 32) {
      long base = (long)s * NQKV + (long)hh * 128;
      float x1 = valid ? qkv[base + j] : 0.f;
      float x2 = valid ? qkv[base + j + 64] : 0.f;
      long ob = ((long)hh * S_PAD + s) * 128;
      qb[ob + j] = f2b(x1 * c - x2 * sn);
      qb[ob + j + 64] = f2b(x2 * c + x1 * sn);
    } else {
      int h = hh - 32;
      long base = (long)s * NQKV + 4096 + (long)h * 128;
      float x1 = valid ? qkv[base + j] : 0.f;
      float x2 = valid ? qkv[base + j + 64] : 0.f;
      long ob = ((long)h * S_PAD + s) * 128;
      kr[ob + j] = valid ? (x1 * c - x2 * sn) : 0.f;
      kr[ob + j + 64] = valid ? (x2 * c + x1 * sn) : 0.f;
    }
  }
}

// ---------------- K stats ----------------
__global__ __launch_bounds__(128) void kstat_partial(const float* __restrict__ kr, float* __restrict__ psum,
                                                     float* __restrict__ pmax) {
  int h = blockIdx.x, chunk = blockIdx.y, d = threadIdx.x;
  float sm = 0.f, mx = 0.f;
  int s0 = chunk * 100, s1 = s0 + 100;
  for (int s = s0; s < s1; ++s) {
    float v = kr[((long)h * S_PAD + s) * 128 + d];
    sm += v;
    mx = fmaxf(mx, fabsf(v));
  }
  psum[(h * 20 + chunk) * 128 + d] = sm;
  pmax[(h * 20 + chunk) * 128 + d] = mx;
}

__global__ __launch_bounds__(128) void kstat_final(const float* __restrict__ psum, const float* __restrict__ pmax,
                                                   float* __restrict__ bias, float* __restrict__ scale) {
  int h = blockIdx.x, d = threadIdx.x;
  float sm = 0.f, mx = 0.f;
  for (int c = 0; c < 20; ++c) {
    sm += psum[(h * 20 + c) * 128 + d];
    mx = fmaxf(mx, pmax[(h * 20 + c) * 128 + d]);
  }
  bias[h * 128 + d] = sm / 2000.0f;
  scale[h * 128 + d] = powf(mx, 0.6f);
}

// ---------------- quant-dequant K -> bf16 [h][s][d] ----------------
__global__ __launch_bounds__(256) void quant_k(const float* __restrict__ kr, const float* __restrict__ bias,
                                               const float* __restrict__ scale, short* __restrict__ kb) {
  int gid = blockIdx.x * 4 + (threadIdx.x >> 6);
  int lane = threadIdx.x & 63;
  int h = gid >> 11, s = gid & 2047;
  long base = ((long)h * S_PAD + s) * 128;
  if (s >= S_LEN) {
    kb[base + lane] = 0;
    kb[base + lane + 64] = 0;
    return;
  }
  float x0 = kr[base + lane], x1 = kr[base + lane + 64];
  float o0, o1;
  if (s >= QUANT_LEN) {
    o0 = x0;
    o1 = x1;
  } else {
    float b0 = bias[h * 128 + lane], b1 = bias[h * 128 + lane + 64];
    float c0 = scale[h * 128 + lane], c1 = scale[h * 128 + lane + 64];
    float kh0 = (x0 - b0) / c0, kh1 = (x1 - b1) / c1;
    float mn0 = kh0, mx0 = kh0, mn1 = kh1, mx1 = kh1;
#pragma unroll
    for (int off = 1; off < 64; off <<= 1) {
      mn0 = fminf(mn0, __shfl_xor(mn0, off));
      mx0 = fmaxf(mx0, __shfl_xor(mx0, off));
      mn1 = fminf(mn1, __shfl_xor(mn1, off));
      mx1 = fmaxf(mx1, __shfl_xor(mx1, off));
    }
    float s0 = fmaxf((mx0 - mn0) / 15.f, 1e-8f), s1 = fmaxf((mx1 - mn1) / 15.f, 1e-8f);
    float q0 = fminf(fmaxf(rintf((kh0 - mn0) / s0), 0.f), 15.f);
    float q1 = fminf(fmaxf(rintf((kh1 - mn1) / s1), 0.f), 15.f);
    o0 = (q0 * s0 + mn0) * c0 + b0;
    o1 = (q1 * s1 + mn1) * c1 + b1;
  }
  kb[base + lane] = f2b(o0);
  kb[base + lane + 64] = f2b(o1);
}

// ---------------- quant-dequant V -> bf16 transposed [h][d][s] ----------------
__global__ __launch_bounds__(256) void quant_v(const float* __restrict__ qkv, short* __restrict__ vt) {
  int gid = blockIdx.x * 4 + (threadIdx.x >> 6);
  int lane = threadIdx.x & 63;
  int h = gid >> 11, s = gid & 2047;
  float o0 = 0.f, o1 = 0.f;
  if (s < S_LEN) {
    long base = (long)s * NQKV + 5120 + (long)h * 128;
    float x0 = qkv[base + lane], x1 = qkv[base + lane + 64];
    if (s >= QUANT_LEN) {
      o0 = x0;
      o1 = x1;
    } else {
      float mn0 = x0, mx0 = x0, mn1 = x1, mx1 = x1;
#pragma unroll
      for (int off = 1; off < 64; off <<= 1) {
        mn0 = fminf(mn0, __shfl_xor(mn0, off));
        mx0 = fmaxf(mx0, __shfl_xor(mx0, off));
        mn1 = fminf(mn1, __shfl_xor(mn1, off));
        mx1 = fmaxf(mx1, __shfl_xor(mx1, off));
      }
      float s0 = fmaxf((mx0 - mn0) / 15.f, 1e-8f), s1 = fmaxf((mx1 - mn1) / 15.f, 1e-8f);
      float q0 = fminf(fmaxf(rintf((x0 - mn0) / s0), 0.f), 15.f);
      float q1 = fminf(fmaxf(rintf((x1 - mn1) / s1), 0.f), 15.f);
      o0 = q0 * s0 + mn0;
      o1 = q1 * s1 + mn1;
    }
  }
  long ob = (long)h * 128 * S_PAD;
  vt[ob + (long)lane * S_PAD + s] = f2b(o0);
  vt[ob + (long)(lane + 64) * S_PAD + s] = f2b(o1);
}

// ---------------- flash attention ----------------
// grid: 1024 blocks, longest q-tiles first; qb [32][2048][128], kb [8][2048][128], vt [8][128][2048]

__global__ __launch_bounds__(256) void flash_attn(const short* __restrict__ qb, const short* __restrict__ kb,
                                                  const short* __restrict__ vt, short* __restrict__ ao) {
  __shared__ short Ks[64][136];
  __shared__ short Vs[128][72];
  __shared__ short Ps[4][16][72];
  int bx = blockIdx.x;
  int qt = 31 - (bx >> 5);  // longest-first scheduling
  int h = bx & 31;
  int kvh = h >> 2;
  int t = threadIdx.x, lane = t & 63, w = t >> 6;
  int lr = lane & 15, lg = lane >> 4;
  int qrow = qt * 64 + w * 16;
  short8 qf[4];
#pragma unroll
  for (int kk = 0; kk < 4; ++kk)
    qf[kk] = *(const short8*)(qb + ((long)h * S_PAD + qrow + lr) * 128 + kk * 32 + lg * 8);
  f32x4 o[8];
#pragma unroll
  for (int nb = 0; nb < 8; ++nb) o[nb] = f32x4{0.f, 0.f, 0.f, 0.f};
  float m_i[4], l_i[4];
#pragma unroll
  for (int i = 0; i < 4; ++i) {
    m_i[i] = -1e30f;
    l_i[i] = 0.f;
  }
  const float sm_scale = 0.08838834764831845f;
  int nkt = qt + 1;
  for (int kt = 0; kt < nkt; ++kt) {
    __syncthreads();
    {
      int r = t >> 2, cc = (t & 3) * 32;
      const short* src = kb + ((long)kvh * S_PAD + kt * 64 + r) * 128 + cc;
#pragma unroll
      for (int j = 0; j < 4; ++j) *(short8*)&Ks[r][cc + j * 8] = *(const short8*)(src + j * 8);
    }
    {
      int d = t >> 1, cc = (t & 1) * 32;
      const short* src = vt + ((long)kvh * 128 + d) * S_PAD + kt * 64 + cc;
#pragma unroll
      for (int j = 0; j < 4; ++j) *(short8*)&Vs[d][cc + j * 8] = *(const short8*)(src + j * 8);
    }
    __syncthreads();
    f32x4 sc[4];
#pragma unroll
    for (int nb = 0; nb < 4; ++nb) sc[nb] = f32x4{0.f, 0.f, 0.f, 0.f};
    __builtin_amdgcn_s_setprio(1);
#pragma unroll
    for (int kk = 0; kk < 4; ++kk) {
#pragma unroll
      for (int nb = 0; nb < 4; ++nb) {
        short8 bk = *(const short8*)&Ks[nb * 16 + lr][kk * 32 + lg * 8];
        sc[nb] = __builtin_amdgcn_mfma_f32_16x16x32_bf16(qf[kk], bk, sc[nb], 0, 0, 0);
      }
    }
    __builtin_amdgcn_s_setprio(0);
    float mrow[4];
#pragma unroll
    for (int i = 0; i < 4; ++i) mrow[i] = -1e30f;
#pragma unroll
    for (int nb = 0; nb < 4; ++nb) {
      int key = kt * 64 + nb * 16 + lr;
#pragma unroll
      for (int i = 0; i < 4; ++i) {
        int qr = qrow + lg * 4 + i;
        float v = sc[nb][i] * sm_scale + (key > qr ? -1e9f : 0.f);
        sc[nb][i] = v;
        mrow[i] = fmaxf(mrow[i], v);
      }
    }
#pragma unroll
    for (int off = 1; off < 16; off <<= 1)
#pragma unroll
      for (int i = 0; i < 4; ++i) mrow[i] = fmaxf(mrow[i], __shfl_xor(mrow[i], off));
    float mnew[4], fac[4], rsum[4];
#pragma unroll
    for (int i = 0; i < 4; ++i) {
      mnew[i] = fmaxf(m_i[i], mrow[i]);
      fac[i] = __expf(m_i[i] - mnew[i]);
      m_i[i] = mnew[i];
      rsum[i] = 0.f;
    }
#pragma unroll
    for (int nb = 0; nb < 4; ++nb)
#pragma unroll
      for (int i = 0; i < 4; ++i) {
        float p = __expf(sc[nb][i] - mnew[i]);
        sc[nb][i] = p;
        rsum[i] += p;
      }
#pragma unroll
    for (int off = 1; off < 16; off <<= 1)
#pragma unroll
      for (int i = 0; i < 4; ++i) rsum[i] += __shfl_xor(rsum[i], off);
#pragma unroll
    for (int i = 0; i < 4; ++i) l_i[i] = l_i[i] * fac[i] + rsum[i];
#pragma unroll
    for (int nb = 0; nb < 8; ++nb)
#pragma unroll
      for (int i = 0; i < 4; ++i) o[nb][i] *= fac[i];
#pragma unroll
    for (int nb = 0; nb < 4; ++nb)
#pragma unroll
      for (int i = 0; i < 4; ++i) Ps[w][lg * 4 + i][nb * 16 + lr] = f2b(sc[nb][i]);
    __builtin_amdgcn_s_setprio(1);
#pragma unroll
    for (int kkk = 0; kkk < 2; ++kkk) {
      short8 pa = *(const short8*)&Ps[w][lr][kkk * 32 + lg * 8];
#pragma unroll
      for (int nb = 0; nb < 8; ++nb) {
        short8 bv = *(const short8*)&Vs[nb * 16 + lr][kkk * 32 + lg * 8];
        o[nb] = __builtin_amdgcn_mfma_f32_16x16x32_bf16(pa, bv, o[nb], 0, 0, 0);
      }
    }
    __builtin_amdgcn_s_setprio(0);
  }
  float linv[4];
#pragma unroll
  for (int i = 0; i < 4; ++i) linv[i] = 1.0f / l_i[i];
#pragma unroll
  for (int nb = 0; nb < 8; ++nb)
#pragma unroll
    for (int i = 0; i < 4; ++i) {
      int s = qrow + lg * 4 + i;
      ao[(long)s * 4096 + h * 128 + nb * 16 + lr] = f2b(o[nb][i] * linv[i]);
    }
}

// ---------------- launcher ----------------

extern "C" void kernel_launch(void* const* d_in, const int* in_sizes, int n_in,
                              void* d_out, int out_size, void* d_ws, size_t ws_size,
                              hipStream_t stream) {
  const float* hidden = (const float*)d_in[0];
  const float* wq = (const float*)d_in[1];
  const float* wk = (const float*)d_in[2];
  const float* wv = (const float*)d_in[3];
  const float* wo = (const float*)d_in[4];
  float* out = (float*)d_out;
  char* ws = (char*)d_ws;
  size_t off = 0;
  auto alloc = [&](size_t bytes) -> void* {
    void* p = ws + off;
    off += (bytes + 255) & ~(size_t)255;
    return p;
  };
  short* wqT = (short*)alloc(4096L * 4096 * 2);
  short* wkvT_hi = (short*)alloc(2048L * 4096 * 2);
  short* wkvT_lo = (short*)alloc(2048L * 4096 * 2);
  float* qkvf = (float*)alloc(2048L * 6144 * 4);
  short* hb_hi = (short*)alloc(2048L * 4096 * 2);
  short* hb_lo = (short*)alloc(2048L * 4096 * 2);
  short* qb2 = (short*)alloc(32L * 2048 * 128 * 2);
  float* kr = (float*)alloc(8L * 2048 * 128 * 4);
  short* kbq = (short*)alloc(8L * 2048 * 128 * 2);
  short* vt = (short*)alloc(8L * 128 * 2048 * 2);
  float* psum = (float*)alloc(8L * 20 * 128 * 4);
  float* pmax = (float*)alloc(8L * 20 * 128 * 4);
  float* kbias = (float*)alloc(1024 * 4);
  float* kscale = (float*)alloc(1024 * 4);
  short* woT = (short*)qkvf;  // alias: qkvf dead after quant_v
  short* ab = hb_hi;          // alias: hb_hi dead after QKV GEMMs

  cvt_hidden2<<<4096, 256, 0, stream>>>(hidden, hb_hi, hb_lo);
  transpose_cvt<<<dim3(128, 128), 256, 0, stream>>>(wq, wqT, 4096, 4096);
  transpose_cvt2<<<dim3(32, 128), 256, 0, stream>>>(wk, wkvT_hi, wkvT_lo, 4096, 1024);
  transpose_cvt2<<<dim3(32, 128), 256, 0, stream>>>(wv, wkvT_hi + 1024L * 4096, wkvT_lo + 1024L * 4096, 4096, 1024);
  gemm_bt<<<dim3(32, 16), 256, 0, stream>>>(hb_hi, wqT, qkvf, 2000, 6144, 4096);
  gemm_bt_split<<<dim3(16, 16), 256, 0, stream>>>(hb_hi, hb_lo, wkvT_hi, wkvT_lo, qkvf + 4096, 2000, 6144, 4096);
  rope_kernel<<<2048, 256, 0, stream>>>(qkvf, qb2, kr);
  kstat_partial<<<dim3(8, 20), 128, 0, stream>>>(kr, psum, pmax);
  kstat_final<<<8, 128, 0, stream>>>(psum, pmax, kbias, kscale);
  quant_k<<<4096, 256, 0, stream>>>(kr, kbias, kscale, kbq);
  quant_v<<<4096, 256, 0, stream>>>(qkvf, vt);
  transpose_cvt<<<dim3(128, 128), 256, 0, stream>>>(wo, woT, 4096, 4096);
  flash_attn<<<1024, 256, 0, stream>>>(qb2, kbq, vt, ab);
  gemm_bt<<<dim3(32, 16), 256, 0, stream>>>(ab, woT, out, 2000, 4096, 4096);
}

// Round 5
// 616.194 us; speedup vs baseline: 1.3505x; 1.1043x over previous
//
#include <hip/hip_runtime.h>
#include <hip/hip_bf16.h>

#define S_LEN 2000
#define S_PAD 2048
#define QKN 5120
#define QUANT_LEN 1920

typedef short short8 __attribute__((ext_vector_type(8)));
typedef float f32x4 __attribute__((ext_vector_type(4)));

__device__ __forceinline__ short f2b(float f) {
  unsigned u = __builtin_bit_cast(unsigned, f);
  u += 0x7fffu + ((u >> 16) & 1u);
  return (short)(u >> 16);
}
__device__ __forceinline__ float b2f(short s) {
  unsigned u = ((unsigned)(unsigned short)s) << 16;
  return __builtin_bit_cast(float, u);
}

// async global->LDS, 16B per lane; lds base must be wave-uniform (HW writes base + lane*16)
__device__ __forceinline__ void gl_lds16(const void* g, void* lds) {
  __builtin_amdgcn_global_load_lds((__attribute__((address_space(1))) void*)(void*)g,
                                   (__attribute__((address_space(3))) void*)lds, 16, 0, 0);
}

// ---------------- conversion kernels ----------------

__global__ __launch_bounds__(256) void cvt_hidden2(const float* __restrict__ src, short* __restrict__ hi,
                                                   short* __restrict__ lo) {
  long base = ((long)blockIdx.x * 256 + threadIdx.x) * 8;
  int row = (int)(base >> 12);
  short8 h, l;
  if (row < S_LEN) {
#pragma unroll
    for (int j = 0; j < 8; ++j) {
      float x = src[base + j];
      short hb = f2b(x);
      h[j] = hb;
      l[j] = f2b(x - b2f(hb));
    }
  } else {
#pragma unroll
    for (int j = 0; j < 8; ++j) { h[j] = 0; l[j] = 0; }
  }
  *(short8*)(hi + base) = h;
  *(short8*)(lo + base) = l;
}

__global__ __launch_bounds__(256) void transpose_cvt(const float* __restrict__ src, short* __restrict__ dst,
                                                     int K, int N) {
  __shared__ float t[32][33];
  int n0 = blockIdx.x * 32, k0 = blockIdx.y * 32;
  int tx = threadIdx.x & 31, ty = threadIdx.x >> 5;
#pragma unroll
  for (int i = 0; i < 4; ++i)
    t[ty + i * 8][tx] = src[(long)(k0 + ty + i * 8) * N + n0 + tx];
  __syncthreads();
#pragma unroll
  for (int i = 0; i < 4; ++i)
    dst[(long)(n0 + ty + i * 8) * K + k0 + tx] = f2b(t[tx][ty + i * 8]);
}

__global__ __launch_bounds__(256) void transpose_cvt2(const float* __restrict__ src, short* __restrict__ dhi,
                                                      short* __restrict__ dlo, int K, int N) {
  __shared__ float t[32][33];
  int n0 = blockIdx.x * 32, k0 = blockIdx.y * 32;
  int tx = threadIdx.x & 31, ty = threadIdx.x >> 5;
#pragma unroll
  for (int i = 0; i < 4; ++i)
    t[ty + i * 8][tx] = src[(long)(k0 + ty + i * 8) * N + n0 + tx];
  __syncthreads();
#pragma unroll
  for (int i = 0; i < 4; ++i) {
    float x = t[tx][ty + i * 8];
    short hb = f2b(x);
    long idx = (long)(n0 + ty + i * 8) * K + k0 + tx;
    dhi[idx] = hb;
    dlo[idx] = f2b(x - b2f(hb));
  }
}

// ---------------- bf16 MFMA GEMM (m97 structure): C[M][*] = A[M][K] * BT[N][K]^T ----------------

__global__ __launch_bounds__(256, 2) void gemm_bt(const short* __restrict__ A, const short* __restrict__ BT,
                                                  float* __restrict__ C, int M_store, int ldc, int K) {
  __shared__ short As[128 * 64];
  __shared__ short Bs[128 * 64];
  int m0 = blockIdx.y * 128, n0 = blockIdx.x * 128;
  int t = threadIdx.x, lane = t & 63, w = t >> 6;
  int wm = w >> 1, wn = w & 1;
  int lr = lane & 15, lg = lane >> 4;
  int srow = lane >> 3, scol = (lane & 7) * 8;
  f32x4 acc[4][4];
#pragma unroll
  for (int mi = 0; mi < 4; ++mi)
#pragma unroll
    for (int ni = 0; ni < 4; ++ni) acc[mi][ni] = f32x4{0.f, 0.f, 0.f, 0.f};
  const int nk = K >> 6;
  const short* Ab = A + (long)(m0 + w * 32 + srow) * K + scol;
  const short* Bb = BT + (long)(n0 + w * 32 + srow) * K + scol;
  for (int kt = 0; kt < nk; ++kt) {
    __syncthreads();
#pragma unroll
    for (int j = 0; j < 4; ++j) {
      int c = w * 4 + j;
      gl_lds16(Ab + (long)j * 8 * K + kt * 64, &As[c * 512]);
      gl_lds16(Bb + (long)j * 8 * K + kt * 64, &Bs[c * 512]);
    }
    __syncthreads();
#pragma unroll
    for (int kk = 0; kk < 2; ++kk) {
      short8 a[4], b[4];
#pragma unroll
      for (int i = 0; i < 4; ++i) a[i] = *(const short8*)&As[(wm * 64 + i * 16 + lr) * 64 + kk * 32 + lg * 8];
#pragma unroll
      for (int i = 0; i < 4; ++i) b[i] = *(const short8*)&Bs[(wn * 64 + i * 16 + lr) * 64 + kk * 32 + lg * 8];
#pragma unroll
      for (int mi = 0; mi < 4; ++mi)
#pragma unroll
        for (int ni = 0; ni < 4; ++ni)
          acc[mi][ni] = __builtin_amdgcn_mfma_f32_16x16x32_bf16(a[mi], b[ni], acc[mi][ni], 0, 0, 0);
    }
  }
#pragma unroll
  for (int mi = 0; mi < 4; ++mi)
#pragma unroll
    for (int i = 0; i < 4; ++i) {
      int row = m0 + wm * 64 + mi * 16 + lg * 4 + i;
      if (row < M_store) {
#pragma unroll
        for (int ni = 0; ni < 4; ++ni)
          C[(long)row * ldc + n0 + wn * 64 + ni * 16 + lr] = acc[mi][ni][i];
      }
    }
}

// split-bf16 GEMM (effective fp32) with split-K: hi*hi + hi*lo + lo*hi.
// blockIdx.z selects a K-slice; partial sums go to Cpart[z][2048][1024].
__global__ __launch_bounds__(256, 1) void gemm_bt_split(const short* __restrict__ Ahi, const short* __restrict__ Alo,
                                                        const short* __restrict__ Bhi, const short* __restrict__ Blo,
                                                        float* __restrict__ Cpart, int M_store, int Ktot, int Kslice) {
  __shared__ short Ash[128 * 64], Asl[128 * 64];
  __shared__ short Bsh[128 * 64], Bsl[128 * 64];
  int m0 = blockIdx.y * 128, n0 = blockIdx.x * 128;
  int bz = blockIdx.z;
  int t = threadIdx.x, lane = t & 63, w = t >> 6;
  int wm = w >> 1, wn = w & 1;
  int lr = lane & 15, lg = lane >> 4;
  int srow = lane >> 3, scol = (lane & 7) * 8;
  f32x4 acc[4][4];
#pragma unroll
  for (int mi = 0; mi < 4; ++mi)
#pragma unroll
    for (int ni = 0; ni < 4; ++ni) acc[mi][ni] = f32x4{0.f, 0.f, 0.f, 0.f};
  const int nk = Kslice >> 6;
  long abase = (long)(m0 + w * 32 + srow) * Ktot + (long)bz * Kslice + scol;
  long bbase = (long)(n0 + w * 32 + srow) * Ktot + (long)bz * Kslice + scol;
  float* C = Cpart + (long)bz * 2048 * 1024;
  for (int kt = 0; kt < nk; ++kt) {
    __syncthreads();
#pragma unroll
    for (int j = 0; j < 4; ++j) {
      int c = w * 4 + j;
      long ao = abase + (long)j * 8 * Ktot + kt * 64;
      long bo = bbase + (long)j * 8 * Ktot + kt * 64;
      gl_lds16(Ahi + ao, &Ash[c * 512]);
      gl_lds16(Alo + ao, &Asl[c * 512]);
      gl_lds16(Bhi + bo, &Bsh[c * 512]);
      gl_lds16(Blo + bo, &Bsl[c * 512]);
    }
    __syncthreads();
#pragma unroll
    for (int kk = 0; kk < 2; ++kk) {
      short8 ah[4], al[4], bh[4], bl[4];
#pragma unroll
      for (int i = 0; i < 4; ++i) {
        int ro = (wm * 64 + i * 16 + lr) * 64 + kk * 32 + lg * 8;
        int co = (wn * 64 + i * 16 + lr) * 64 + kk * 32 + lg * 8;
        ah[i] = *(const short8*)&Ash[ro];
        al[i] = *(const short8*)&Asl[ro];
        bh[i] = *(const short8*)&Bsh[co];
        bl[i] = *(const short8*)&Bsl[co];
      }
#pragma unroll
      for (int mi = 0; mi < 4; ++mi)
#pragma unroll
        for (int ni = 0; ni < 4; ++ni) {
          acc[mi][ni] = __builtin_amdgcn_mfma_f32_16x16x32_bf16(ah[mi], bh[ni], acc[mi][ni], 0, 0, 0);
          acc[mi][ni] = __builtin_amdgcn_mfma_f32_16x16x32_bf16(ah[mi], bl[ni], acc[mi][ni], 0, 0, 0);
          acc[mi][ni] = __builtin_amdgcn_mfma_f32_16x16x32_bf16(al[mi], bh[ni], acc[mi][ni], 0, 0, 0);
        }
    }
  }
#pragma unroll
  for (int mi = 0; mi < 4; ++mi)
#pragma unroll
    for (int i = 0; i < 4; ++i) {
      int row = m0 + wm * 64 + mi * 16 + lg * 4 + i;
      if (row < M_store) {
#pragma unroll
        for (int ni = 0; ni < 4; ++ni)
          C[(long)row * 1024 + n0 + wn * 64 + ni * 16 + lr] = acc[mi][ni][i];
      }
    }
}

// ---------------- RoPE ----------------
// qkvf row layout [s][5120]: q cols 0..4095 (h*128+d), k cols 4096..5119
__global__ __launch_bounds__(256) void rope_kernel(const float* __restrict__ qkv, short* __restrict__ qb,
                                                   float* __restrict__ kr) {
  __shared__ float invt[64];
  if (threadIdx.x < 64) invt[threadIdx.x] = (float)pow(10000.0, -(double)threadIdx.x / 64.0);
  __syncthreads();
  int s = blockIdx.x;
  bool valid = s < S_LEN;
  for (int p = threadIdx.x; p < 2560; p += 256) {
    int hh = p >> 6, j = p & 63;
    float ang = (float)s * invt[j];
    float c = cosf(ang), sn = sinf(ang);
    if (hh < 32) {
      long base = (long)s * QKN + (long)hh * 128;
      float x1 = valid ? qkv[base + j] : 0.f;
      float x2 = valid ? qkv[base + j + 64] : 0.f;
      long ob = ((long)hh * S_PAD + s) * 128;
      qb[ob + j] = f2b(x1 * c - x2 * sn);
      qb[ob + j + 64] = f2b(x2 * c + x1 * sn);
    } else {
      int h = hh - 32;
      long base = (long)s * QKN + 4096 + (long)h * 128;
      float x1 = valid ? qkv[base + j] : 0.f;
      float x2 = valid ? qkv[base + j + 64] : 0.f;
      long ob = ((long)h * S_PAD + s) * 128;
      kr[ob + j] = valid ? (x1 * c - x2 * sn) : 0.f;
      kr[ob + j + 64] = valid ? (x2 * c + x1 * sn) : 0.f;
    }
  }
}

// ---------------- K stats ----------------
__global__ __launch_bounds__(128) void kstat_partial(const float* __restrict__ kr, float* __restrict__ psum,
                                                     float* __restrict__ pmax) {
  int h = blockIdx.x, chunk = blockIdx.y, d = threadIdx.x;
  float sm = 0.f, mx = 0.f;
  int s0 = chunk * 100, s1 = s0 + 100;
  for (int s = s0; s < s1; ++s) {
    float v = kr[((long)h * S_PAD + s) * 128 + d];
    sm += v;
    mx = fmaxf(mx, fabsf(v));
  }
  psum[(h * 20 + chunk) * 128 + d] = sm;
  pmax[(h * 20 + chunk) * 128 + d] = mx;
}

__global__ __launch_bounds__(128) void kstat_final(const float* __restrict__ psum, const float* __restrict__ pmax,
                                                   float* __restrict__ bias, float* __restrict__ scale) {
  int h = blockIdx.x, d = threadIdx.x;
  float sm = 0.f, mx = 0.f;
  for (int c = 0; c < 20; ++c) {
    sm += psum[(h * 20 + c) * 128 + d];
    mx = fmaxf(mx, pmax[(h * 20 + c) * 128 + d]);
  }
  bias[h * 128 + d] = sm / 2000.0f;
  scale[h * 128 + d] = powf(mx, 0.6f);
}

// ---------------- quant-dequant K -> bf16 [h][s][d] ----------------
__global__ __launch_bounds__(256) void quant_k(const float* __restrict__ kr, const float* __restrict__ bias,
                                               const float* __restrict__ scale, short* __restrict__ kb) {
  int gid = blockIdx.x * 4 + (threadIdx.x >> 6);
  int lane = threadIdx.x & 63;
  int h = gid >> 11, s = gid & 2047;
  long base = ((long)h * S_PAD + s) * 128;
  if (s >= S_LEN) {
    kb[base + lane] = 0;
    kb[base + lane + 64] = 0;
    return;
  }
  float x0 = kr[base + lane], x1 = kr[base + lane + 64];
  float o0, o1;
  if (s >= QUANT_LEN) {
    o0 = x0;
    o1 = x1;
  } else {
    float b0 = bias[h * 128 + lane], b1 = bias[h * 128 + lane + 64];
    float c0 = scale[h * 128 + lane], c1 = scale[h * 128 + lane + 64];
    float kh0 = (x0 - b0) / c0, kh1 = (x1 - b1) / c1;
    float mn0 = kh0, mx0 = kh0, mn1 = kh1, mx1 = kh1;
#pragma unroll
    for (int off = 1; off < 64; off <<= 1) {
      mn0 = fminf(mn0, __shfl_xor(mn0, off));
      mx0 = fmaxf(mx0, __shfl_xor(mx0, off));
      mn1 = fminf(mn1, __shfl_xor(mn1, off));
      mx1 = fmaxf(mx1, __shfl_xor(mx1, off));
    }
    float s0 = fmaxf((mx0 - mn0) / 15.f, 1e-8f), s1 = fmaxf((mx1 - mn1) / 15.f, 1e-8f);
    float q0 = fminf(fmaxf(rintf((kh0 - mn0) / s0), 0.f), 15.f);
    float q1 = fminf(fmaxf(rintf((kh1 - mn1) / s1), 0.f), 15.f);
    o0 = (q0 * s0 + mn0) * c0 + b0;
    o1 = (q1 * s1 + mn1) * c1 + b1;
  }
  kb[base + lane] = f2b(o0);
  kb[base + lane + 64] = f2b(o1);
}

// ---------------- quant-dequant V (from 4 split-K partials) -> bf16 transposed [h][d][s] ----------------
__global__ __launch_bounds__(256) void quant_v(const float* __restrict__ vp, short* __restrict__ vt) {
  int gid = blockIdx.x * 4 + (threadIdx.x >> 6);
  int lane = threadIdx.x & 63;
  int h = gid >> 11, s = gid & 2047;
  float o0 = 0.f, o1 = 0.f;
  if (s < S_LEN) {
    long b = (long)s * 1024 + h * 128;
    const long PS = 2048L * 1024;
    float x0 = vp[b + lane] + vp[PS + b + lane] + vp[2 * PS + b + lane] + vp[3 * PS + b + lane];
    float x1 = vp[b + lane + 64] + vp[PS + b + lane + 64] + vp[2 * PS + b + lane + 64] + vp[3 * PS + b + lane + 64];
    if (s >= QUANT_LEN) {
      o0 = x0;
      o1 = x1;
    } else {
      float mn0 = x0, mx0 = x0, mn1 = x1, mx1 = x1;
#pragma unroll
      for (int off = 1; off < 64; off <<= 1) {
        mn0 = fminf(mn0, __shfl_xor(mn0, off));
        mx0 = fmaxf(mx0, __shfl_xor(mx0, off));
        mn1 = fminf(mn1, __shfl_xor(mn1, off));
        mx1 = fmaxf(mx1, __shfl_xor(mx1, off));
      }
      float s0 = fmaxf((mx0 - mn0) / 15.f, 1e-8f), s1 = fmaxf((mx1 - mn1) / 15.f, 1e-8f);
      float q0 = fminf(fmaxf(rintf((x0 - mn0) / s0), 0.f), 15.f);
      float q1 = fminf(fmaxf(rintf((x1 - mn1) / s1), 0.f), 15.f);
      o0 = q0 * s0 + mn0;
      o1 = q1 * s1 + mn1;
    }
  }
  long ob = (long)h * 128 * S_PAD;
  vt[ob + (long)lane * S_PAD + s] = f2b(o0);
  vt[ob + (long)(lane + 64) * S_PAD + s] = f2b(o1);
}

// ---------------- flash attention ----------------
// grid: 1024 blocks, longest q-tiles first; qb [32][2048][128], kb [8][2048][128], vt [8][128][2048]

__global__ __launch_bounds__(256) void flash_attn(const short* __restrict__ qb, const short* __restrict__ kb,
                                                  const short* __restrict__ vt, short* __restrict__ ao) {
  __shared__ short Ks[64][136];
  __shared__ short Vs[128][72];
  __shared__ short Ps[4][16][72];
  int bx = blockIdx.x;
  int qt = 31 - (bx >> 5);  // longest-first scheduling
  int h = bx & 31;
  int kvh = h >> 2;
  int t = threadIdx.x, lane = t & 63, w = t >> 6;
  int lr = lane & 15, lg = lane >> 4;
  int qrow = qt * 64 + w * 16;
  short8 qf[4];
#pragma unroll
  for (int kk = 0; kk < 4; ++kk)
    qf[kk] = *(const short8*)(qb + ((long)h * S_PAD + qrow + lr) * 128 + kk * 32 + lg * 8);
  f32x4 o[8];
#pragma unroll
  for (int nb = 0; nb < 8; ++nb) o[nb] = f32x4{0.f, 0.f, 0.f, 0.f};
  float m_i[4], l_i[4];
#pragma unroll
  for (int i = 0; i < 4; ++i) {
    m_i[i] = -1e30f;
    l_i[i] = 0.f;
  }
  const float sm_scale = 0.08838834764831845f;
  int nkt = qt + 1;
  for (int kt = 0; kt < nkt; ++kt) {
    __syncthreads();
    {
      int r = t >> 2, cc = (t & 3) * 32;
      const short* src = kb + ((long)kvh * S_PAD + kt * 64 + r) * 128 + cc;
#pragma unroll
      for (int j = 0; j < 4; ++j) *(short8*)&Ks[r][cc + j * 8] = *(const short8*)(src + j * 8);
    }
    {
      int d = t >> 1, cc = (t & 1) * 32;
      const short* src = vt + ((long)kvh * 128 + d) * S_PAD + kt * 64 + cc;
#pragma unroll
      for (int j = 0; j < 4; ++j) *(short8*)&Vs[d][cc + j * 8] = *(const short8*)(src + j * 8);
    }
    __syncthreads();
    f32x4 sc[4];
#pragma unroll
    for (int nb = 0; nb < 4; ++nb) sc[nb] = f32x4{0.f, 0.f, 0.f, 0.f};
    __builtin_amdgcn_s_setprio(1);
#pragma unroll
    for (int kk = 0; kk < 4; ++kk) {
#pragma unroll
      for (int nb = 0; nb < 4; ++nb) {
        short8 bk = *(const short8*)&Ks[nb * 16 + lr][kk * 32 + lg * 8];
        sc[nb] = __builtin_amdgcn_mfma_f32_16x16x32_bf16(qf[kk], bk, sc[nb], 0, 0, 0);
      }
    }
    __builtin_amdgcn_s_setprio(0);
    float mrow[4];
#pragma unroll
    for (int i = 0; i < 4; ++i) mrow[i] = -1e30f;
#pragma unroll
    for (int nb = 0; nb < 4; ++nb) {
      int key = kt * 64 + nb * 16 + lr;
#pragma unroll
      for (int i = 0; i < 4; ++i) {
        int qr = qrow + lg * 4 + i;
        float v = sc[nb][i] * sm_scale + (key > qr ? -1e9f : 0.f);
        sc[nb][i] = v;
        mrow[i] = fmaxf(mrow[i], v);
      }
    }
#pragma unroll
    for (int off = 1; off < 16; off <<= 1)
#pragma unroll
      for (int i = 0; i < 4; ++i) mrow[i] = fmaxf(mrow[i], __shfl_xor(mrow[i], off));
    float mnew[4], fac[4], rsum[4];
#pragma unroll
    for (int i = 0; i < 4; ++i) {
      mnew[i] = fmaxf(m_i[i], mrow[i]);
      fac[i] = __expf(m_i[i] - mnew[i]);
      m_i[i] = mnew[i];
      rsum[i] = 0.f;
    }
#pragma unroll
    for (int nb = 0; nb < 4; ++nb)
#pragma unroll
      for (int i = 0; i < 4; ++i) {
        float p = __expf(sc[nb][i] - mnew[i]);
        sc[nb][i] = p;
        rsum[i] += p;
      }
#pragma unroll
    for (int off = 1; off < 16; off <<= 1)
#pragma unroll
      for (int i = 0; i < 4; ++i) rsum[i] += __shfl_xor(rsum[i], off);
#pragma unroll
    for (int i = 0; i < 4; ++i) l_i[i] = l_i[i] * fac[i] + rsum[i];
#pragma unroll
    for (int nb = 0; nb < 8; ++nb)
#pragma unroll
      for (int i = 0; i < 4; ++i) o[nb][i] *= fac[i];
#pragma unroll
    for (int nb = 0; nb < 4; ++nb)
#pragma unroll
      for (int i = 0; i < 4; ++i) Ps[w][lg * 4 + i][nb * 16 + lr] = f2b(sc[nb][i]);
    __builtin_amdgcn_s_setprio(1);
#pragma unroll
    for (int kkk = 0; kkk < 2; ++kkk) {
      short8 pa = *(const short8*)&Ps[w][lr][kkk * 32 + lg * 8];
#pragma unroll
      for (int nb = 0; nb < 8; ++nb) {
        short8 bv = *(const short8*)&Vs[nb * 16 + lr][kkk * 32 + lg * 8];
        o[nb] = __builtin_amdgcn_mfma_f32_16x16x32_bf16(pa, bv, o[nb], 0, 0, 0);
      }
    }
    __builtin_amdgcn_s_setprio(0);
  }
  float linv[4];
#pragma unroll
  for (int i = 0; i < 4; ++i) linv[i] = 1.0f / l_i[i];
#pragma unroll
  for (int nb = 0; nb < 8; ++nb)
#pragma unroll
    for (int i = 0; i < 4; ++i) {
      int s = qrow + lg * 4 + i;
      ao[(long)s * 4096 + h * 128 + nb * 16 + lr] = f2b(o[nb][i] * linv[i]);
    }
}

// ---------------- launcher ----------------

extern "C" void kernel_launch(void* const* d_in, const int* in_sizes, int n_in,
                              void* d_out, int out_size, void* d_ws, size_t ws_size,
                              hipStream_t stream) {
  const float* hidden = (const float*)d_in[0];
  const float* wq = (const float*)d_in[1];
  const float* wk = (const float*)d_in[2];
  const float* wv = (const float*)d_in[3];
  const float* wo = (const float*)d_in[4];
  float* out = (float*)d_out;
  char* ws = (char*)d_ws;
  size_t off = 0;
  auto alloc = [&](size_t bytes) -> void* {
    void* p = ws + off;
    off += (bytes + 255) & ~(size_t)255;
    return p;
  };
  short* wqkT = (short*)alloc(5120L * 4096 * 2);     // [wq;wk]^T bf16
  short* wvT_hi = (short*)alloc(1024L * 4096 * 2);   // wv^T hi
  short* wvT_lo = (short*)alloc(1024L * 4096 * 2);   // wv^T lo
  float* qkvf = (float*)alloc(2048L * 5120 * 4);     // Q,K projections fp32
  float* vpart = (float*)alloc(4L * 2048 * 1024 * 4);// V split-K partials
  short* hb_hi = (short*)alloc(2048L * 4096 * 2);
  short* hb_lo = (short*)alloc(2048L * 4096 * 2);
  short* qb2 = (short*)alloc(32L * 2048 * 128 * 2);
  float* kr = (float*)alloc(8L * 2048 * 128 * 4);
  short* kbq = (short*)alloc(8L * 2048 * 128 * 2);
  short* vt = (short*)alloc(8L * 128 * 2048 * 2);
  float* psum = (float*)alloc(8L * 20 * 128 * 4);
  float* pmax = (float*)alloc(8L * 20 * 128 * 4);
  float* kbias = (float*)alloc(1024 * 4);
  float* kscale = (float*)alloc(1024 * 4);
  short* woT = (short*)qkvf;  // alias: qkvf dead after rope (41.9MB >= 33.5MB)
  short* ab = hb_hi;          // alias: hb_hi dead after the two projection GEMMs

  cvt_hidden2<<<4096, 256, 0, stream>>>(hidden, hb_hi, hb_lo);
  transpose_cvt<<<dim3(128, 128), 256, 0, stream>>>(wq, wqkT, 4096, 4096);
  transpose_cvt<<<dim3(32, 128), 256, 0, stream>>>(wk, wqkT + 4096L * 4096, 4096, 1024);
  transpose_cvt2<<<dim3(32, 128), 256, 0, stream>>>(wv, wvT_hi, wvT_lo, 4096, 1024);
  // Q+K projection: plain bf16, N=5120
  gemm_bt<<<dim3(40, 16), 256, 0, stream>>>(hb_hi, wqkT, qkvf, 2000, 5120, 4096);
  // V projection: split-bf16 (fp32-accurate), split-K=4
  gemm_bt_split<<<dim3(8, 16, 4), 256, 0, stream>>>(hb_hi, hb_lo, wvT_hi, wvT_lo, vpart, 2000, 4096, 1024);
  rope_kernel<<<2048, 256, 0, stream>>>(qkvf, qb2, kr);
  transpose_cvt<<<dim3(128, 128), 256, 0, stream>>>(wo, woT, 4096, 4096);
  kstat_partial<<<dim3(8, 20), 128, 0, stream>>>(kr, psum, pmax);
  kstat_final<<<8, 128, 0, stream>>>(psum, pmax, kbias, kscale);
  quant_k<<<4096, 256, 0, stream>>>(kr, kbias, kscale, kbq);
  quant_v<<<4096, 256, 0, stream>>>(vpart, vt);
  flash_attn<<<1024, 256, 0, stream>>>(qb2, kbq, vt, ab);
  gemm_bt<<<dim3(32, 16), 256, 0, stream>>>(ab, woT, out, 2000, 4096, 4096);
}